// Round 6
// baseline (361.368 us; speedup 1.0000x reference)
//
#include <hip/hip_runtime.h>
#include <math.h>

#define BB 16
#define QQ 900
#define CC 91
#define TT 100
#define BT (BB * TT)        // 1600
#define NTHREADS 256
#define NSLOT 15            // ceil(900/64) row slots per lane

__device__ __forceinline__ unsigned ordkey(float f) {
    unsigned u = __float_as_uint(f);
    return (u & 0x80000000u) ? ~u : (u | 0x80000000u);
}

__device__ __forceinline__ unsigned long long u64min(unsigned long long a, unsigned long long b) {
    return a < b ? a : b;
}

// pack (key,row,col) -> u64; lexicographic == numpy flat-index argmin order
// key:32 bits @20 | row:10 bits @10 | col:10 bits @0   (row<=899, col<=99)
__device__ __forceinline__ unsigned long long packkrc(unsigned key, int row, int col) {
    return ((unsigned long long)key << 20) | ((unsigned)row << 10) | (unsigned)col;
}

// ---------------------------------------------------------------------------
// Kernel 1: cost[b,q,j], float4 stores; for j<100 also atomicMin the packed
// (key,row,col) into colmin[b*128+j] — fuses greedy's phase-1 column scan.
// ---------------------------------------------------------------------------
__global__ __launch_bounds__(NTHREADS) void cost_kernel(
    const float* __restrict__ logits,
    const float* __restrict__ pred,
    const int*   __restrict__ tlab,
    const float* __restrict__ tbox,
    float*       __restrict__ cost,
    unsigned long long* __restrict__ colmin)
{
    const int bq = blockIdx.x;
    const int b  = bq / QQ;
    const int q  = bq - b * QQ;
    __shared__ float sig[CC];

    const float* lg = logits + (size_t)bq * CC;
    for (int c = threadIdx.x; c < CC; c += NTHREADS) {
        float x = lg[c];
        sig[c] = 1.0f / (1.0f + expf(-x));
    }

    const float4 p = *(const float4*)(pred + (size_t)bq * 4);
    const float p_x0 = p.x - 0.5f * p.z;
    const float p_y0 = p.y - 0.5f * p.w;
    const float p_x1 = p.x + 0.5f * p.z;
    const float p_y1 = p.y + 0.5f * p.w;
    const float area1 = (p_x1 - p_x0) * (p_y1 - p_y0);

    __syncthreads();

    float* crow = cost + (size_t)bq * BT;
    for (int j4 = threadIdx.x; j4 < BT / 4; j4 += NTHREADS) {
        const int j = j4 * 4;
        float vals[4];
        #pragma unroll
        for (int k = 0; k < 4; ++k) {
            float4 t = *(const float4*)(tbox + (size_t)(j + k) * 4);
            int id = tlab[j + k];
            float cclass = -sig[id];
            float cbbox = ((fabsf(p.x - t.x) + fabsf(p.y - t.y)) + fabsf(p.z - t.z)) + fabsf(p.w - t.w);

            float t_x0 = t.x - 0.5f * t.z, t_y0 = t.y - 0.5f * t.w;
            float t_x1 = t.x + 0.5f * t.z, t_y1 = t.y + 0.5f * t.w;
            float area2 = (t_x1 - t_x0) * (t_y1 - t_y0);

            float ltx = fmaxf(p_x0, t_x0), lty = fmaxf(p_y0, t_y0);
            float rbx = fminf(p_x1, t_x1), rby = fminf(p_y1, t_y1);
            float iw = fmaxf(rbx - ltx, 0.0f), ih = fmaxf(rby - lty, 0.0f);
            float inter = iw * ih;
            float uni = (area1 + area2) - inter;
            float iou = inter / uni;

            float ex0 = fminf(p_x0, t_x0), ey0 = fminf(p_y0, t_y0);
            float ex1 = fmaxf(p_x1, t_x1), ey1 = fmaxf(p_y1, t_y1);
            float ew = fmaxf(ex1 - ex0, 0.0f), eh = fmaxf(ey1 - ey0, 0.0f);
            float ae = ew * eh;
            float giou = iou - (ae - uni) / ae;

            vals[k] = (cbbox + cclass) + (-giou);
        }
        *(float4*)(crow + j) = make_float4(vals[0], vals[1], vals[2], vals[3]);

        if (j < TT) {   // cols 0..99: fold into per-(b,col) minima
            #pragma unroll
            for (int k = 0; k < 4; ++k)
                atomicMin(&colmin[b * 128 + j + k], packkrc(ordkey(vals[k]), q, j + k));
        }
    }
}

// ---------------------------------------------------------------------------
// Kernel 2: greedy matcher, single wave per batch, column-minima already in
// colmin. Per step: 6-level u64 butterfly. Rescan (expected ~6/batch total)
// only when the matched row was another column's cached argmin.
// ---------------------------------------------------------------------------
__global__ __launch_bounds__(64, 1) void greedy_kernel(
    const float* __restrict__ cost,
    const unsigned long long* __restrict__ colmin,
    float*       __restrict__ rows_out,
    float*       __restrict__ cols_out)
{
    const int b    = blockIdx.x;
    const int lane = threadIdx.x;
    const float* cb = cost + (size_t)b * QQ * BT;

    unsigned long long cola = colmin[b * 128 + lane];
    unsigned long long colb = (lane < TT - 64) ? colmin[b * 128 + 64 + lane] : ~0ULL;

    // row-validity: bits 0..13 all lanes (r<=895); bit 14 only lanes 0..3
    unsigned rowok = (lane < 4) ? 0x7FFFu : 0x3FFFu;

    for (int step = 0; step < TT; ++step) {
        unsigned long long m = u64min(cola, colb);
        #pragma unroll
        for (int off = 1; off < 64; off <<= 1)
            m = u64min(m, __shfl_xor(m, off, 64));

        const int rstar = (int)((m >> 10) & 0x3FF);
        const int cstar = (int)(m & 0x3FF);

        if (lane == 0) {
            rows_out[b * TT + step] = (float)rstar;
            cols_out[b * TT + step] = (float)cstar;
        }

        if (lane == cstar)        cola = ~0ULL;
        if (lane + 64 == cstar)   colb = ~0ULL;
        if (lane == (rstar & 63)) rowok &= ~(1u << (rstar >> 6));

        // columns whose cached argmin row just died (rare): ~0ULL decodes to
        // row 1023 which never equals rstar<=899, so removed cols never hit.
        unsigned long long hitsA = __ballot((int)((cola >> 10) & 0x3FF) == rstar);
        unsigned long long hitsB = __ballot((int)((colb >> 10) & 0x3FF) == rstar);

        while (hitsA | hitsB) {
            int c;
            if (hitsA) { c = (int)__ffsll(hitsA) - 1;      hitsA &= hitsA - 1; }
            else       { c = (int)__ffsll(hitsB) - 1 + 64; hitsB &= hitsB - 1; }

            // cooperative rescan of column c (wave-uniform)
            unsigned long long best = ~0ULL;
            #pragma unroll
            for (int i = 0; i < NSLOT; ++i) {
                if ((rowok >> i) & 1u) {
                    const int r = i * 64 + lane;
                    float v = cb[(size_t)r * BT + c];
                    best = u64min(best, packkrc(ordkey(v), r, c));
                }
            }
            #pragma unroll
            for (int off = 1; off < 64; off <<= 1)
                best = u64min(best, __shfl_xor(best, off, 64));

            if (lane == c)      cola = best;
            if (lane + 64 == c) colb = best;
        }
    }
}

extern "C" void kernel_launch(void* const* d_in, const int* in_sizes, int n_in,
                              void* d_out, int out_size, void* d_ws, size_t ws_size,
                              hipStream_t stream) {
    const float* logits = (const float*)d_in[0];   // [16,900,91]
    const float* pred   = (const float*)d_in[1];   // [16,900,4]
    const int*   tlab   = (const int*)d_in[2];     // [16,100]
    const float* tbox   = (const float*)d_in[3];   // [16,100,4]

    float* out = (float*)d_out;
    float* cost = out;                              // 23,040,000
    float* rows = out + (size_t)BB * QQ * BT;       // 1600
    float* cols = rows + (size_t)BB * TT;           // 1600

    unsigned long long* colmin = (unsigned long long*)d_ws;   // [16][128]

    // 0xFF.. == ~0ULL sentinel (d_ws poison 0xAA is NOT > all packed keys)
    hipMemsetAsync(colmin, 0xFF, (size_t)BB * 128 * sizeof(unsigned long long), stream);
    cost_kernel<<<BB * QQ, NTHREADS, 0, stream>>>(logits, pred, tlab, tbox, cost, colmin);
    greedy_kernel<<<BB, 64, 0, stream>>>(cost, colmin, rows, cols);
}